// Round 13
// baseline (316.138 us; speedup 1.0000x reference)
//
#include <hip/hip_runtime.h>
#include <hip/hip_bf16.h>
#include <math.h>

#define N_BATCH 128
#define C_CH    512
#define HF      38
#define WF      38
#define K1      25088   // 512*49
#define NH      4096
#define NCLS    21
#define NBOX    80
#define STEPS1  784     // K1/32
#define STEPS2  128     // NH/32

typedef __attribute__((ext_vector_type(8))) short s16x8;
typedef __attribute__((ext_vector_type(4))) float f32x4;

// fp32 -> 3x bf16 split (RNE): x ~= b0+b1+b2, residual ~ |x|*2^-25
__device__ __forceinline__ unsigned short bf_rne(float x) {
  unsigned u = __float_as_uint(x);
  return (unsigned short)((u + 0x7FFFu + ((u >> 16) & 1u)) >> 16);
}
__device__ __forceinline__ float bf2f(unsigned short b) {
  return __uint_as_float(((unsigned)b) << 16);
}
__device__ __forceinline__ void split3(float x, unsigned short& q0,
                                       unsigned short& q1, unsigned short& q2) {
  q0 = bf_rne(x); float r1 = x - bf2f(q0);
  q1 = bf_rne(r1); float r2 = r1 - bf2f(q1);
  q2 = bf_rne(r2);
}

__device__ __forceinline__ void gload16(const void* g, void* l) {
  __builtin_amdgcn_global_load_lds(
      (const __attribute__((address_space(1))) unsigned int*)g,
      (__attribute__((address_space(3))) unsigned int*)l, 16, 0, 0);
}

// ---------------------------------------------------------------------------
// Kernel 1: ROI crop + adaptive 7x7 maxpool -> 3 bf16 planes (group-major
// fragment order). Pool results staged in LDS; 49 threads then write 8
// consecutive k each as contiguous 16B ushort4 pairs (no 2B scatter).
// ---------------------------------------------------------------------------
__global__ __launch_bounds__(256) void pool_kernel(
    const float* __restrict__ x, const int* __restrict__ rp,
    unsigned short* __restrict__ Asw) {
  const int n = blockIdx.y, cb = blockIdx.x, tid = threadIdx.x;
  const int r = rp[n*4+0], c = rp[n*4+1], w = rp[n*4+2], h = rp[n*4+3];
  __shared__ float tile[8][24][25];
  __shared__ float pout[392];
  const int ch = tid >> 5, l32 = tid & 31;
  const float* xc = x + (((size_t)(n*C_CH + cb*8 + ch))*HF + c)*WF + r;
  for (int y = 0; y < h; ++y)
    for (int xx = l32; xx < w; xx += 32)
      tile[ch][y][xx] = xc[y*WF + xx];
  __syncthreads();
  for (int o = tid; o < 8*49; o += 256) {
    int ch2 = o / 49, ij = o - ch2*49, i = ij / 7, j = ij - i*7;
    int rs = (i*h)/7, re = ((i+1)*h + 6)/7;
    int cs = (j*w)/7, ce = ((j+1)*w + 6)/7;
    float m = -INFINITY;
    for (int y = rs; y < re; ++y)
      for (int xx = cs; xx < ce; ++xx)
        m = fmaxf(m, tile[ch2][y][xx]);
    pout[o] = m;
  }
  __syncthreads();
  if (tid < 49) {
    const int mt = n >> 4, mlo = n & 15;
    const int kl0 = tid * 8;
    const int kg0 = cb*392 + kl0;           // 8-aligned, within one S chunk
    const int S = kg0 >> 5, kg = (kg0 >> 3) & 3;
    size_t base = ((size_t)S*8 + mt)*1536 + (size_t)(kg*16 + mlo)*8;
    unsigned short q[3][8];
    #pragma unroll
    for (int e = 0; e < 8; ++e)
      split3(pout[kl0 + e], q[0][e], q[1][e], q[2][e]);
    #pragma unroll
    for (int p = 0; p < 3; ++p) {
      ushort4 lo; lo.x=q[p][0]; lo.y=q[p][1]; lo.z=q[p][2]; lo.w=q[p][3];
      ushort4 hi; hi.x=q[p][4]; hi.y=q[p][5]; hi.z=q[p][6]; hi.w=q[p][7];
      *(ushort4*)(Asw + base + p*512)     = lo;
      *(ushort4*)(Asw + base + p*512 + 4) = hi;
    }
  }
}

// ---------------------------------------------------------------------------
// Kernel 2: barrier-free split-K MFMA GEMM, templated on NT (n-tiles/wave).
// BM=128, BN=2*NT*16; 4 waves as (wr=wv>>1, wc=wv&1): wave = 4mt x NT nt.
// nt-granular pipeline: split(nt+1) interleaves with MFMA burst(nt).
// BUGFIX vs v8/v9: the A-window prefetch (LOADA of step s+1) runs in the
// LAST burst of the step — after every nt has consumed w[ml]. v8/v9 ran it
// in the first burst, so nt>=1 used next-step A fragments (shifted GEMM).
// Sync: robust counted wait (vmcnt(SB) after issuing SB stage ops) +
// sched_barrier to pin ds_reads. No __syncthreads.
// ---------------------------------------------------------------------------
template<int NT, int MINW>
__global__ __launch_bounds__(256, MINW) void gemm_v10(
    const unsigned short* __restrict__ Asw, const float* __restrict__ B,
    float* __restrict__ part, const int nsteps) {
  constexpr int NCOLS = NT * 16;        // cols per wave
  constexpr int SB = 2 * NT;            // gload16 ops per stage
  constexpr int LPR = NT * 4;           // staging lanes per row
  constexpr int RPO = 64 / LPR;         // rows per stage op
  __shared__ float Bsm[4][2][32][NCOLS];
  const int tid = threadIdx.x, lane = tid & 63, wv = tid >> 6;
  const int wr = wv >> 1, wc = wv & 1;
  const int nb = blockIdx.x, ks = blockIdx.y;
  const int l15 = lane & 15, lq = lane >> 4;
  const unsigned short* Ag = Asw + (size_t)ks*nsteps*12288 + lane*8;
  const int srow = lane / LPR, scol = lane % LPR;
  const float* Bg = B + ((size_t)ks*nsteps*32 + srow)*NH
                  + (size_t)nb*(2*NCOLS) + wc*NCOLS;
  float* ldsb = &Bsm[wv][0][0][0];

  f32x4 acc[4][NT];
  #pragma unroll
  for (int i = 0; i < 4; ++i)
    #pragma unroll
    for (int j = 0; j < NT; ++j) acc[i][j] = (f32x4){0.f, 0.f, 0.f, 0.f};

  s16x8 w0[4], w1[4], w2[4];            // A window: this wave's 4 mt
#define LOADA(slot, g) do { \
    const unsigned short* ap_ = Ag + (size_t)(g)*1536; \
    w0[slot] = *(const s16x8*)ap_; \
    w1[slot] = *(const s16x8*)(ap_ + 512); \
    w2[slot] = *(const s16x8*)(ap_ + 1024); } while (0)

#define STAGEB(s, buf) do { \
    float* dst_ = ldsb + (buf)*(32*NCOLS); \
    _Pragma("unroll") \
    for (int i_ = 0; i_ < SB; ++i_) { \
      const int row_ = i_*RPO + srow; \
      gload16(Bg + ((size_t)(s)*32 + (size_t)i_*RPO)*NH \
                 + ((scol*4) ^ (8*((row_ >> 3) & 3))), dst_ + i_*256); \
    } } while (0)

#define SPLITNT(nt, B0, B1, B2) do { \
    _Pragma("unroll") \
    for (int e_ = 0; e_ < 8; ++e_) { \
      float xv_ = bb[(lq*8 + e_)*NCOLS + (((nt)*16 + l15) ^ (lq*8))]; \
      unsigned short q0_, q1_, q2_; split3(xv_, q0_, q1_, q2_); \
      B0[e_] = (short)q0_; B1[e_] = (short)q1_; B2[e_] = (short)q2_; \
    } } while (0)

  // DO_LOADA only in the LAST burst of a step (after all nt consumed w[]).
#define BURST(nt, B0, B1, B2, DO_LOADA) do { \
    _Pragma("unroll") \
    for (int ml_ = 0; ml_ < 4; ++ml_) { \
      const s16x8 a0_ = w0[ml_], a1_ = w1[ml_], a2_ = w2[ml_]; \
      if (DO_LOADA) LOADA(ml_, (s + 1)*8 + wr*4 + ml_); \
      f32x4 cc_ = acc[ml_][nt]; \
      cc_ = __builtin_amdgcn_mfma_f32_16x16x32_bf16(a0_, B0, cc_, 0, 0, 0); \
      cc_ = __builtin_amdgcn_mfma_f32_16x16x32_bf16(a0_, B1, cc_, 0, 0, 0); \
      cc_ = __builtin_amdgcn_mfma_f32_16x16x32_bf16(a1_, B0, cc_, 0, 0, 0); \
      cc_ = __builtin_amdgcn_mfma_f32_16x16x32_bf16(a0_, B2, cc_, 0, 0, 0); \
      cc_ = __builtin_amdgcn_mfma_f32_16x16x32_bf16(a1_, B1, cc_, 0, 0, 0); \
      cc_ = __builtin_amdgcn_mfma_f32_16x16x32_bf16(a2_, B0, cc_, 0, 0, 0); \
      acc[ml_][nt] = cc_; \
    } } while (0)

  STAGEB(0, 0);
  LOADA(0, wr*4 + 0); LOADA(1, wr*4 + 1);
  LOADA(2, wr*4 + 2); LOADA(3, wr*4 + 3);

  for (int s = 0; s < nsteps; ++s) {
    if (s + 1 < nsteps) {
      STAGEB(s + 1, (s + 1) & 1);
      // Robust: only the SB newest VMEM ops may remain outstanding; B(s)
      // and everything older is guaranteed retired (spill-proof).
      if constexpr (NT == 4) {
        asm volatile("s_waitcnt vmcnt(8)" ::: "memory");
      } else {
        asm volatile("s_waitcnt vmcnt(4)" ::: "memory");
      }
    } else {
      asm volatile("s_waitcnt vmcnt(0)" ::: "memory");
    }
    __builtin_amdgcn_sched_barrier(0);   // pin ds_reads after the wait
    const float* bb = ldsb + (s & 1)*(32*NCOLS);
    s16x8 pA0, pA1, pA2, pB0, pB1, pB2;   // two nt fragment slots
    SPLITNT(0, pA0, pA1, pA2);
    if constexpr (NT == 4) {
      SPLITNT(1, pB0, pB1, pB2); BURST(0, pA0, pA1, pA2, false);
      SPLITNT(2, pA0, pA1, pA2); BURST(1, pB0, pB1, pB2, false);
      SPLITNT(3, pB0, pB1, pB2); BURST(2, pA0, pA1, pA2, false);
      BURST(3, pB0, pB1, pB2, true);
    } else {
      SPLITNT(1, pB0, pB1, pB2); BURST(0, pA0, pA1, pA2, false);
      BURST(1, pB0, pB1, pB2, true);
    }
  }
#undef LOADA
#undef STAGEB
#undef SPLITNT
#undef BURST
  // epilogue: C/D layout row=(lane>>4)*4+rr, col=lane&15
  float* Pb = part + (size_t)ks*N_BATCH*NH + (size_t)nb*(2*NCOLS) + wc*NCOLS;
  #pragma unroll
  for (int ml = 0; ml < 4; ++ml)
    #pragma unroll
    for (int nt = 0; nt < NT; ++nt)
      #pragma unroll
      for (int rr = 0; rr < 4; ++rr)
        Pb[(size_t)((wr*4 + ml)*16 + lq*4 + rr)*NH + nt*16 + l15]
            = acc[ml][nt][rr];
}

// ---------------------------------------------------------------------------
// Kernel 3: reduce split-K partials + bias + relu.
// mode 0: emit group-major swizzled bf16 planes (A of next GEMM).
// mode 1: write fp32 rows.
// ---------------------------------------------------------------------------
__global__ __launch_bounds__(256) void reduce_k(
    const float* __restrict__ part, const float* __restrict__ bias,
    unsigned short* __restrict__ AswOut, float* __restrict__ f32out,
    int KS, int mode) {
  const int idx = blockIdx.x*256 + threadIdx.x;     // float4 idx, 131072 total
  float4 s = ((const float4*)part)[idx];
  for (int k2 = 1; k2 < KS; ++k2) {
    float4 p = ((const float4*)part)[(size_t)k2*131072 + idx];
    s.x += p.x; s.y += p.y; s.z += p.z; s.w += p.w;
  }
  float4 bv = ((const float4*)bias)[idx & 1023];
  float v[4];
  v[0] = fmaxf(s.x + bv.x, 0.f); v[1] = fmaxf(s.y + bv.y, 0.f);
  v[2] = fmaxf(s.z + bv.z, 0.f); v[3] = fmaxf(s.w + bv.w, 0.f);
  if (mode == 1) {
    float4 o; o.x = v[0]; o.y = v[1]; o.z = v[2]; o.w = v[3];
    ((float4*)f32out)[idx] = o;
  } else {
    int m = idx >> 10, k = (idx & 1023) * 4;
    int S = k >> 5, kg = (k >> 3) & 3, e0 = k & 7;
    size_t base = ((size_t)S*8 + (m >> 4))*1536
                + (size_t)(kg*16 + (m & 15))*8 + e0;
    unsigned short q[3][4];
    #pragma unroll
    for (int e = 0; e < 4; ++e) split3(v[e], q[0][e], q[1][e], q[2][e]);
    #pragma unroll
    for (int p = 0; p < 3; ++p) {
      ushort4 st; st.x=q[p][0]; st.y=q[p][1]; st.z=q[p][2]; st.w=q[p][3];
      *(ushort4*)(AswOut + base + p*512) = st;
    }
  }
}

// ---------------------------------------------------------------------------
// Kernel 4a: transpose Wcls|Wbox into WT[101][4096]
// ---------------------------------------------------------------------------
__global__ __launch_bounds__(256) void head_transpose(
    const float* __restrict__ Wcls, const float* __restrict__ Wbox,
    float* __restrict__ WT) {
  const int c = blockIdx.x;
  const float* src; int stride;
  if (c < NCLS) { src = Wcls + c; stride = NCLS; }
  else          { src = Wbox + (c - NCLS); stride = NBOX; }
  for (int k = threadIdx.x; k < NH; k += 256)
    WT[(size_t)c*NH + k] = src[(size_t)k*stride];
}

// ---------------------------------------------------------------------------
// Kernel 4b: one wave per (n, col): float4 dot over K=4096 + shuffle reduce
// ---------------------------------------------------------------------------
__global__ __launch_bounds__(256) void head_dots(
    const float* __restrict__ h2, const float* __restrict__ WT,
    float* __restrict__ hout) {
  const int n = blockIdx.y;
  const int wv = threadIdx.x >> 6, lane = threadIdx.x & 63;
  const int c = blockIdx.x * 4 + wv;
  if (c >= NCLS + NBOX) return;
  const float4* hp = (const float4*)(h2 + (size_t)n*NH);
  const float4* wp = (const float4*)(WT + (size_t)c*NH);
  float s0=0.f, s1=0.f, s2=0.f, s3=0.f;
  #pragma unroll
  for (int it = 0; it < 16; ++it) {
    float4 a = hp[it*64 + lane];
    float4 b = wp[it*64 + lane];
    s0 = fmaf(a.x, b.x, s0); s1 = fmaf(a.y, b.y, s1);
    s2 = fmaf(a.z, b.z, s2); s3 = fmaf(a.w, b.w, s3);
  }
  float v = (s0 + s1) + (s2 + s3);
  #pragma unroll
  for (int m = 32; m >= 1; m >>= 1) v += __shfl_xor(v, m, 64);
  if (lane == 0) hout[n*128 + c] = v;
}

// ---------------------------------------------------------------------------
// Kernel 4c: softmax(21) + bbox(80) from stored dots.
// ---------------------------------------------------------------------------
__global__ __launch_bounds__(128) void head_final(
    const float* __restrict__ hout, const int* __restrict__ rp,
    float* __restrict__ out) {
  const int n = blockIdx.x, tid = threadIdx.x;
  __shared__ float logits[NCLS];
  __shared__ float red[2];
  if (tid < NCLS) logits[tid] = hout[n*128 + tid];
  __syncthreads();
  if (tid == 0) {
    float m = logits[0];
    for (int i = 1; i < NCLS; ++i) m = fmaxf(m, logits[i]);
    float s = 0.f;
    for (int i = 0; i < NCLS; ++i) s += expf(logits[i] - m);
    red[0] = m; red[1] = s;
  }
  __syncthreads();
  if (tid < NCLS) {
    out[(size_t)n*NCLS + tid] = expf(logits[tid] - red[0]) / red[1];
  } else if (tid < NCLS + NBOX) {
    const int j = tid - NCLS;
    const float t  = hout[n*128 + tid];
    const float rf = (float)rp[n*4+0];
    const float cf = (float)rp[n*4+1];
    const float wf = (float)rp[n*4+2];
    const float hf = (float)rp[n*4+3];
    float p;
    switch (j & 3) {
      case 0:  p = ceilf (__fmul_rn(__fadd_rn(__fmul_rn(wf, t), rf), 16.f)) - 1.f; break;
      case 1:  p = ceilf (__fmul_rn(__fadd_rn(__fmul_rn(hf, t), cf), 16.f)) - 1.f; break;
      case 2:  p = floorf(__fmul_rn(__fmul_rn(wf, expf(t)), 16.f)) + 1.f; break;
      default: p = floorf(__fmul_rn(__fmul_rn(hf, expf(t)), 16.f)) + 1.f; break;
    }
    out[(size_t)N_BATCH*NCLS + (size_t)n*NBOX + j] = p;
  }
}

// ---------------------------------------------------------------------------
extern "C" void kernel_launch(void* const* d_in, const int* in_sizes, int n_in,
                              void* d_out, int out_size, void* d_ws, size_t ws_size,
                              hipStream_t stream) {
  const float* x    = (const float*)d_in[0];
  const int*   rp   = (const int*)  d_in[1];
  const float* W1   = (const float*)d_in[2];
  const float* b1   = (const float*)d_in[3];
  const float* W2   = (const float*)d_in[4];
  const float* b2   = (const float*)d_in[5];
  const float* Wcls = (const float*)d_in[6];
  const float* Wbox = (const float*)d_in[7];
  float* out = (float*)d_out;

  // ws: Asw1 | Asw2 | h2f | WT | hout | part  (~60 MB; ws ≈ 1.6 GB)
  char* wp = (char*)d_ws;
  unsigned short* Asw1 = (unsigned short*)wp; wp += (size_t)STEPS1*24576;
  unsigned short* Asw2 = (unsigned short*)wp; wp += (size_t)STEPS2*24576;
  float* h2f = (float*)wp;            wp += (size_t)N_BATCH*NH*4;
  float* WT  = (float*)wp;            wp += (size_t)(NCLS+NBOX)*NH*4;
  float* hout = (float*)wp;           wp += (size_t)N_BATCH*128*4;
  float* part = (float*)wp;
  const size_t fixed = (size_t)(wp - (char*)d_ws);
  const size_t slab = (size_t)N_BATCH*NH*4;       // 2 MB per partial
  int KS1 = 16, KS2 = 16;
  if (fixed + 16*slab > ws_size) { KS1 = 8; KS2 = 8; }

  pool_kernel<<<dim3(64, 128), 256, 0, stream>>>(x, rp, Asw1);
  head_transpose<<<dim3(NCLS + NBOX), 256, 0, stream>>>(Wcls, Wbox, WT);

  // GEMM1: BN=128 (NT=4), grid 32x16 = 512 blocks = 2/CU
  gemm_v10<4, 2><<<dim3(32, KS1), 256, 0, stream>>>(Asw1, W1, part, STEPS1/KS1);
  reduce_k<<<dim3(512), 256, 0, stream>>>(part, b1, Asw2, nullptr, KS1, 0);

  // GEMM2: BN=64 (NT=2), grid 64x16 = 1024 blocks
  gemm_v10<2, 2><<<dim3(64, KS2), 256, 0, stream>>>(Asw2, W2, part, STEPS2/KS2);
  reduce_k<<<dim3(512), 256, 0, stream>>>(part, b2, nullptr, h2f, KS2, 1);

  head_dots<<<dim3(26, 128), 256, 0, stream>>>(h2f, WT, hout);
  head_final<<<dim3(128), 128, 0, stream>>>(hout, rp, out);
}

// Round 14
// 252.281 us; speedup vs baseline: 1.2531x; 1.2531x over previous
//
#include <hip/hip_runtime.h>
#include <hip/hip_bf16.h>
#include <math.h>

#define N_BATCH 128
#define C_CH    512
#define HF      38
#define WF      38
#define K1      25088   // 512*49
#define NH      4096
#define NCLS    21
#define NBOX    80
#define STEPS1  784     // K1/32
#define STEPS2  128     // NH/32

typedef __attribute__((ext_vector_type(8))) short s16x8;
typedef __attribute__((ext_vector_type(4))) float f32x4;

__device__ __forceinline__ unsigned short bf_rne(float x) {
  unsigned u = __float_as_uint(x);
  return (unsigned short)((u + 0x7FFFu + ((u >> 16) & 1u)) >> 16);
}
__device__ __forceinline__ float bf2f(unsigned short b) {
  return __uint_as_float(((unsigned)b) << 16);
}
// fp32 -> 2x bf16 split (RNE): x ~= b0+b1, residual ~ |x|*2^-18
__device__ __forceinline__ void split2(float x, unsigned short& q0,
                                       unsigned short& q1) {
  q0 = bf_rne(x); float r1 = x - bf2f(q0);
  q1 = bf_rne(r1);
}

__device__ __forceinline__ void gload16(const void* g, void* l) {
  __builtin_amdgcn_global_load_lds(
      (const __attribute__((address_space(1))) unsigned int*)g,
      (__attribute__((address_space(3))) unsigned int*)l, 16, 0, 0);
}

// ---------------------------------------------------------------------------
// Kernel 1: ROI crop + adaptive 7x7 maxpool -> 2 bf16 planes (group-major
// fragment order): group g = S*8 + mt; short addr = g*1024 + plane*512
// + (kg*16 + mlo)*8 + e. Pool results staged in LDS; 49 threads write 8
// consecutive k each as contiguous 16B ushort4 pairs.
// ---------------------------------------------------------------------------
__global__ __launch_bounds__(256) void pool_kernel(
    const float* __restrict__ x, const int* __restrict__ rp,
    unsigned short* __restrict__ Asw) {
  const int n = blockIdx.y, cb = blockIdx.x, tid = threadIdx.x;
  const int r = rp[n*4+0], c = rp[n*4+1], w = rp[n*4+2], h = rp[n*4+3];
  __shared__ float tile[8][24][25];
  __shared__ float pout[392];
  const int ch = tid >> 5, l32 = tid & 31;
  const float* xc = x + (((size_t)(n*C_CH + cb*8 + ch))*HF + c)*WF + r;
  for (int y = 0; y < h; ++y)
    for (int xx = l32; xx < w; xx += 32)
      tile[ch][y][xx] = xc[y*WF + xx];
  __syncthreads();
  for (int o = tid; o < 8*49; o += 256) {
    int ch2 = o / 49, ij = o - ch2*49, i = ij / 7, j = ij - i*7;
    int rs = (i*h)/7, re = ((i+1)*h + 6)/7;
    int cs = (j*w)/7, ce = ((j+1)*w + 6)/7;
    float m = -INFINITY;
    for (int y = rs; y < re; ++y)
      for (int xx = cs; xx < ce; ++xx)
        m = fmaxf(m, tile[ch2][y][xx]);
    pout[o] = m;
  }
  __syncthreads();
  if (tid < 49) {
    const int mt = n >> 4, mlo = n & 15;
    const int kl0 = tid * 8;
    const int kg0 = cb*392 + kl0;           // 8-aligned, within one S chunk
    const int S = kg0 >> 5, kg = (kg0 >> 3) & 3;
    size_t base = ((size_t)S*8 + mt)*1024 + (size_t)(kg*16 + mlo)*8;
    unsigned short q[2][8];
    #pragma unroll
    for (int e = 0; e < 8; ++e)
      split2(pout[kl0 + e], q[0][e], q[1][e]);
    #pragma unroll
    for (int p = 0; p < 2; ++p) {
      ushort4 lo; lo.x=q[p][0]; lo.y=q[p][1]; lo.z=q[p][2]; lo.w=q[p][3];
      ushort4 hi; hi.x=q[p][4]; hi.y=q[p][5]; hi.z=q[p][6]; hi.w=q[p][7];
      *(ushort4*)(Asw + base + p*512)     = lo;
      *(ushort4*)(Asw + base + p*512 + 4) = hi;
    }
  }
}

// ---------------------------------------------------------------------------
// Kernel 2: barrier-free split-K MFMA GEMM, 2-way split x 3 products.
// BM=128, BN=128, BK=32, 4 waves (wr,wc): wave = 4mt x 4nt of 16x16.
// A: 2 bf16 planes, 4-slot register window, one-step lookahead (v7 pattern:
//    w[ml] copied to locals, then overwritten — consumed within iteration ml).
// B: wave-private dbuf 8KB LDS slice via global_load_lds, pre-swizzled cols
//    (2-way banks, free); split2 in-register.
// Sync: robust counted wait — after issuing the 8 stage ops of s+1, wait
// vmcnt(8): only those 8 may remain outstanding, so B(s) + A(s) + any spill
// ops are guaranteed retired. No __syncthreads, no sched_barrier.
// Now HBM-bound by design: W1 stream 411 MB ~ 65-75 us floor.
// ---------------------------------------------------------------------------
__global__ __launch_bounds__(256, 2) void gemm_v11(
    const unsigned short* __restrict__ Asw, const float* __restrict__ B,
    float* __restrict__ part, const int nsteps) {
  __shared__ float Bsm[4][2][32][64];   // [wave][dbuf][k][col'] = 64 KB
  const int tid = threadIdx.x, lane = tid & 63, wv = tid >> 6;
  const int wr = wv >> 1, wc = wv & 1;
  const int nb = blockIdx.x, ks = blockIdx.y;
  const int l15 = lane & 15, lq = lane >> 4;
  const unsigned short* Ag = Asw + (size_t)ks*nsteps*8192 + lane*8;
  const int srow4 = lane >> 4, scol16 = lane & 15;
  const float* Bg = B + ((size_t)ks*nsteps*32 + srow4)*NH
                  + (size_t)nb*128 + wc*64;
  float* ldsb = &Bsm[wv][0][0][0];

  f32x4 acc[4][4];
  #pragma unroll
  for (int i = 0; i < 4; ++i)
    #pragma unroll
    for (int j = 0; j < 4; ++j) acc[i][j] = (f32x4){0.f, 0.f, 0.f, 0.f};

  s16x8 w0[4], w1[4];                   // A window: this wave's 4 mt, 2 planes
#define LOADA(slot, g) do { \
    const unsigned short* ap_ = Ag + (size_t)(g)*1024; \
    w0[slot] = *(const s16x8*)ap_; \
    w1[slot] = *(const s16x8*)(ap_ + 512); } while (0)

#define STAGEB(s, buf) do { \
    float* dst_ = ldsb + (buf)*2048; \
    _Pragma("unroll") \
    for (int i_ = 0; i_ < 8; ++i_) \
      gload16(Bg + ((size_t)(s)*32 + i_*4)*NH \
                 + ((scol16*4) ^ (8*((i_ >> 1) & 3))), dst_ + i_*256); \
    } while (0)

  STAGEB(0, 0);
  LOADA(0, wr*4 + 0); LOADA(1, wr*4 + 1);
  LOADA(2, wr*4 + 2); LOADA(3, wr*4 + 3);

  for (int s = 0; s < nsteps; ++s) {
    if (s + 1 < nsteps) {
      STAGEB(s + 1, (s + 1) & 1);
      asm volatile("s_waitcnt vmcnt(8)" ::: "memory");  // B(s)+A(s) landed
    } else {
      asm volatile("s_waitcnt vmcnt(0)" ::: "memory");
    }
    // B fragments: lane needs B[k=lq*8+e][col=nt*16+l15] at LDS
    // (row, col ^ (8*lq)); 2-way banks (free). split2 -> 2 frags per nt.
    const float* bb = ldsb + (s & 1)*2048;
    s16x8 bf0[4], bf1[4];
    #pragma unroll
    for (int nt = 0; nt < 4; ++nt) {
      #pragma unroll
      for (int e = 0; e < 8; ++e) {
        float xv = bb[(lq*8 + e)*64 + ((nt*16 + l15) ^ (lq*8))];
        unsigned short q0, q1; split2(xv, q0, q1);
        bf0[nt][e] = (short)q0; bf1[nt][e] = (short)q1;
      }
    }
    #pragma unroll
    for (int ml = 0; ml < 4; ++ml) {
      const s16x8 a0 = w0[ml], a1 = w1[ml];
      LOADA(ml, (s + 1)*8 + wr*4 + ml);   // next step (overrun stays in ws)
      #pragma unroll
      for (int nt = 0; nt < 4; ++nt) {
        f32x4 cc = acc[ml][nt];
        cc = __builtin_amdgcn_mfma_f32_16x16x32_bf16(a0, bf0[nt], cc, 0, 0, 0);
        cc = __builtin_amdgcn_mfma_f32_16x16x32_bf16(a0, bf1[nt], cc, 0, 0, 0);
        cc = __builtin_amdgcn_mfma_f32_16x16x32_bf16(a1, bf0[nt], cc, 0, 0, 0);
        acc[ml][nt] = cc;
      }
    }
  }
#undef LOADA
#undef STAGEB
  // epilogue: C/D layout row=(lane>>4)*4+rr, col=lane&15
  float* Pb = part + (size_t)ks*N_BATCH*NH + (size_t)nb*128 + wc*64;
  #pragma unroll
  for (int ml = 0; ml < 4; ++ml)
    #pragma unroll
    for (int nt = 0; nt < 4; ++nt)
      #pragma unroll
      for (int rr = 0; rr < 4; ++rr)
        Pb[(size_t)((wr*4 + ml)*16 + lq*4 + rr)*NH + nt*16 + l15]
            = acc[ml][nt][rr];
}

// ---------------------------------------------------------------------------
// Kernel 3: reduce split-K partials + bias + relu.
// mode 0: emit group-major 2-plane bf16 (A of next GEMM). mode 1: fp32 rows.
// ---------------------------------------------------------------------------
__global__ __launch_bounds__(256) void reduce_k(
    const float* __restrict__ part, const float* __restrict__ bias,
    unsigned short* __restrict__ AswOut, float* __restrict__ f32out,
    int KS, int mode) {
  const int idx = blockIdx.x*256 + threadIdx.x;     // float4 idx, 131072 total
  float4 s = ((const float4*)part)[idx];
  for (int k2 = 1; k2 < KS; ++k2) {
    float4 p = ((const float4*)part)[(size_t)k2*131072 + idx];
    s.x += p.x; s.y += p.y; s.z += p.z; s.w += p.w;
  }
  float4 bv = ((const float4*)bias)[idx & 1023];
  float v[4];
  v[0] = fmaxf(s.x + bv.x, 0.f); v[1] = fmaxf(s.y + bv.y, 0.f);
  v[2] = fmaxf(s.z + bv.z, 0.f); v[3] = fmaxf(s.w + bv.w, 0.f);
  if (mode == 1) {
    float4 o; o.x = v[0]; o.y = v[1]; o.z = v[2]; o.w = v[3];
    ((float4*)f32out)[idx] = o;
  } else {
    int m = idx >> 10, k = (idx & 1023) * 4;
    int S = k >> 5, kg = (k >> 3) & 3, e0 = k & 7;
    size_t base = ((size_t)S*8 + (m >> 4))*1024
                + (size_t)(kg*16 + (m & 15))*8 + e0;
    unsigned short q[2][4];
    #pragma unroll
    for (int e = 0; e < 4; ++e) split2(v[e], q[0][e], q[1][e]);
    #pragma unroll
    for (int p = 0; p < 2; ++p) {
      ushort4 st; st.x=q[p][0]; st.y=q[p][1]; st.z=q[p][2]; st.w=q[p][3];
      *(ushort4*)(AswOut + base + p*512) = st;
    }
  }
}

// ---------------------------------------------------------------------------
// Kernel 4a: transpose Wcls|Wbox into WT[101][4096]
// ---------------------------------------------------------------------------
__global__ __launch_bounds__(256) void head_transpose(
    const float* __restrict__ Wcls, const float* __restrict__ Wbox,
    float* __restrict__ WT) {
  const int c = blockIdx.x;
  const float* src; int stride;
  if (c < NCLS) { src = Wcls + c; stride = NCLS; }
  else          { src = Wbox + (c - NCLS); stride = NBOX; }
  for (int k = threadIdx.x; k < NH; k += 256)
    WT[(size_t)c*NH + k] = src[(size_t)k*stride];
}

// ---------------------------------------------------------------------------
// Kernel 4b: one wave per (n, col): float4 dot over K=4096 + shuffle reduce
// ---------------------------------------------------------------------------
__global__ __launch_bounds__(256) void head_dots(
    const float* __restrict__ h2, const float* __restrict__ WT,
    float* __restrict__ hout) {
  const int n = blockIdx.y;
  const int wv = threadIdx.x >> 6, lane = threadIdx.x & 63;
  const int c = blockIdx.x * 4 + wv;
  if (c >= NCLS + NBOX) return;
  const float4* hp = (const float4*)(h2 + (size_t)n*NH);
  const float4* wp = (const float4*)(WT + (size_t)c*NH);
  float s0=0.f, s1=0.f, s2=0.f, s3=0.f;
  #pragma unroll
  for (int it = 0; it < 16; ++it) {
    float4 a = hp[it*64 + lane];
    float4 b = wp[it*64 + lane];
    s0 = fmaf(a.x, b.x, s0); s1 = fmaf(a.y, b.y, s1);
    s2 = fmaf(a.z, b.z, s2); s3 = fmaf(a.w, b.w, s3);
  }
  float v = (s0 + s1) + (s2 + s3);
  #pragma unroll
  for (int m = 32; m >= 1; m >>= 1) v += __shfl_xor(v, m, 64);
  if (lane == 0) hout[n*128 + c] = v;
}

// ---------------------------------------------------------------------------
// Kernel 4c: softmax(21) + bbox(80) from stored dots.
// ---------------------------------------------------------------------------
__global__ __launch_bounds__(128) void head_final(
    const float* __restrict__ hout, const int* __restrict__ rp,
    float* __restrict__ out) {
  const int n = blockIdx.x, tid = threadIdx.x;
  __shared__ float logits[NCLS];
  __shared__ float red[2];
  if (tid < NCLS) logits[tid] = hout[n*128 + tid];
  __syncthreads();
  if (tid == 0) {
    float m = logits[0];
    for (int i = 1; i < NCLS; ++i) m = fmaxf(m, logits[i]);
    float s = 0.f;
    for (int i = 0; i < NCLS; ++i) s += expf(logits[i] - m);
    red[0] = m; red[1] = s;
  }
  __syncthreads();
  if (tid < NCLS) {
    out[(size_t)n*NCLS + tid] = expf(logits[tid] - red[0]) / red[1];
  } else if (tid < NCLS + NBOX) {
    const int j = tid - NCLS;
    const float t  = hout[n*128 + tid];
    const float rf = (float)rp[n*4+0];
    const float cf = (float)rp[n*4+1];
    const float wf = (float)rp[n*4+2];
    const float hf = (float)rp[n*4+3];
    float p;
    switch (j & 3) {
      case 0:  p = ceilf (__fmul_rn(__fadd_rn(__fmul_rn(wf, t), rf), 16.f)) - 1.f; break;
      case 1:  p = ceilf (__fmul_rn(__fadd_rn(__fmul_rn(hf, t), cf), 16.f)) - 1.f; break;
      case 2:  p = floorf(__fmul_rn(__fmul_rn(wf, expf(t)), 16.f)) + 1.f; break;
      default: p = floorf(__fmul_rn(__fmul_rn(hf, expf(t)), 16.f)) + 1.f; break;
    }
    out[(size_t)N_BATCH*NCLS + (size_t)n*NBOX + j] = p;
  }
}

// ---------------------------------------------------------------------------
extern "C" void kernel_launch(void* const* d_in, const int* in_sizes, int n_in,
                              void* d_out, int out_size, void* d_ws, size_t ws_size,
                              hipStream_t stream) {
  const float* x    = (const float*)d_in[0];
  const int*   rp   = (const int*)  d_in[1];
  const float* W1   = (const float*)d_in[2];
  const float* b1   = (const float*)d_in[3];
  const float* W2   = (const float*)d_in[4];
  const float* b2   = (const float*)d_in[5];
  const float* Wcls = (const float*)d_in[6];
  const float* Wbox = (const float*)d_in[7];
  float* out = (float*)d_out;

  // ws: Asw1 (12.8MB) | Asw2 (2.1MB) | h2f | WT | hout | part (~51 MB total)
  char* wp = (char*)d_ws;
  unsigned short* Asw1 = (unsigned short*)wp; wp += (size_t)STEPS1*16384;
  unsigned short* Asw2 = (unsigned short*)wp; wp += (size_t)STEPS2*16384;
  float* h2f = (float*)wp;            wp += (size_t)N_BATCH*NH*4;
  float* WT  = (float*)wp;            wp += (size_t)(NCLS+NBOX)*NH*4;
  float* hout = (float*)wp;           wp += (size_t)N_BATCH*128*4;
  float* part = (float*)wp;
  const size_t fixed = (size_t)(wp - (char*)d_ws);
  const size_t slab = (size_t)N_BATCH*NH*4;       // 2 MB per partial
  int KS1 = 16, KS2 = 16;
  if (fixed + 16*slab > ws_size) { KS1 = 8; KS2 = 8; }

  pool_kernel<<<dim3(64, 128), 256, 0, stream>>>(x, rp, Asw1);
  head_transpose<<<dim3(NCLS + NBOX), 256, 0, stream>>>(Wcls, Wbox, WT);

  gemm_v11<<<dim3(32, KS1), 256, 0, stream>>>(Asw1, W1, part, STEPS1/KS1);
  reduce_k<<<dim3(512), 256, 0, stream>>>(part, b1, Asw2, nullptr, KS1, 0);

  gemm_v11<<<dim3(32, KS2), 256, 0, stream>>>(Asw2, W2, part, STEPS2/KS2);
  reduce_k<<<dim3(512), 256, 0, stream>>>(part, b2, nullptr, h2f, KS2, 1);

  head_dots<<<dim3(26, 128), 256, 0, stream>>>(h2f, WT, hout);
  head_final<<<dim3(128), 128, 0, stream>>>(hout, rp, out);
}